// Round 8
// baseline (132.141 us; speedup 1.0000x reference)
//
#include <hip/hip_runtime.h>
#include <hip/hip_bf16.h>

typedef __attribute__((ext_vector_type(8))) short bf16x8;
typedef __attribute__((ext_vector_type(4))) float f32x4;

__device__ __forceinline__ unsigned short f2bf(float f) {
  unsigned int u = __float_as_uint(f);
  u += 0x7FFFu + ((u >> 16) & 1u);   // RTNE
  return (unsigned short)(u >> 16);
}

__device__ __forceinline__ bf16x8 pack8(float4 lo, float4 hi) {
  union { unsigned int u[4]; bf16x8 v; } r;
  asm("v_cvt_pk_bf16_f32 %0, %1, %2" : "=v"(r.u[0]) : "v"(lo.x), "v"(lo.y));
  asm("v_cvt_pk_bf16_f32 %0, %1, %2" : "=v"(r.u[1]) : "v"(lo.z), "v"(lo.w));
  asm("v_cvt_pk_bf16_f32 %0, %1, %2" : "=v"(r.u[2]) : "v"(hi.x), "v"(hi.y));
  asm("v_cvt_pk_bf16_f32 %0, %1, %2" : "=v"(r.u[3]) : "v"(hi.z), "v"(hi.w));
  return r.v;
}

__device__ __forceinline__ void gload16(const void* g, void* l) {
  __builtin_amdgcn_global_load_lds(
      (const __attribute__((address_space(1))) void*)g,
      (__attribute__((address_space(3))) void*)l, 16, 0, 0);
}

__host__ __device__ constexpr int prOffset(int l) {
  return (l == 0) ? 0 : (l == 1) ? 3072 : (l == 2) ? 3840 : 4032;
}

// ---------------- x -> bf16 (ws) --------------------------------------------
__global__ __launch_bounds__(256) void cvt_x(const float* __restrict__ x,
                                             unsigned short* __restrict__ xb) {
  const int i = blockIdx.x * 256 + threadIdx.x;          // 131072 float4s
  const float4 v = ((const float4*)x)[i];
  ushort4 pk = {f2bf(v.x), f2bf(v.y), f2bf(v.z), f2bf(v.w)};
  ((ushort4*)xb)[i] = pk;
}

// ---------------- wavelet level (1024 threads, padded ab, b128 scans) -------
template<int L>
__device__ __forceinline__ void level_fwd(float* cur, float* tmp, float* ab,
                                          float* pr, float* thrL, float* thrH,
                                          const float* __restrict__ scl, int tid) {
  constexpr int HALF = 32 >> L, LOG2 = 5 - L, HH = HALF * HALF, TOT = 4 * HH;
  constexpr int H = HALF * 2;
  constexpr int ST = HALF + 4;                 // padded stride (16B-aligned rows)
  constexpr float P = 0.4f * (float)(HALF - 1);
  constexpr int K = (int)P;
  constexpr float FRAC = P - (float)K;
  const float s0 = scl[4 * L + 0], s1 = scl[4 * L + 1];
  const float s2 = scl[4 * L + 2], s3 = scl[4 * L + 3];
  // DWT (raw) -> tmp; fused scaled-abs -> padded ab
  for (int e = tid; e < HH; e += 1024) {
    const int i = e >> LOG2, j = e & (HALF - 1);
    const float a = cur[(i * 2) * H + j * 2];
    const float b = cur[(i * 2) * H + j * 2 + 1];
    const float c = cur[(i * 2 + 1) * H + j * 2];
    const float d = cur[(i * 2 + 1) * H + j * 2 + 1];
    const float vA = (((a + b) + c) + d) * 0.5f;
    const float vH = (((a - b) + c) - d) * 0.5f;
    const float vV = (((a + b) - c) - d) * 0.5f;
    const float vD = (((a - b) - c) + d) * 0.5f;
    tmp[e]          = vA;  ab[(0 * HALF + i) * ST + j] = fabsf(vA * s0);
    tmp[HH + e]     = vH;  ab[(1 * HALF + i) * ST + j] = fabsf(vH * s1);
    tmp[2 * HH + e] = vV;  ab[(2 * HALF + i) * ST + j] = fabsf(vV * s2);
    tmp[3 * HH + e] = vD;  ab[(3 * HALF + i) * ST + j] = fabsf(vD * s3);
  }
  __syncthreads();
  // counting selection: ranks K,K+1 per row; row scan via float4 (padded banks)
  constexpr int CH = (TOT >= 1024) ? TOT / 1024 : 1;
  {
    const int base = tid * CH;
    if (base < TOT) {
      const int row = base >> LOG2;
      const int c0 = base & (HALF - 1);
      const float* rp = &ab[row * ST];
      float v[CH]; int clt[CH], ceq[CH];
#pragma unroll
      for (int c = 0; c < CH; ++c) { v[c] = rp[c0 + c]; clt[c] = 0; ceq[c] = 0; }
#pragma unroll
      for (int rq = 0; rq < HALF / 4; ++rq) {
        const float4 q = *(const float4*)&rp[rq * 4];
        float qa[4] = {q.x, q.y, q.z, q.w};
#pragma unroll
        for (int z = 0; z < 4; ++z) {
#pragma unroll
          for (int c = 0; c < CH; ++c) {
            clt[c] += (qa[z] < v[c]) ? 1 : 0;
            ceq[c] += (qa[z] == v[c]) ? 1 : 0;
          }
        }
      }
#pragma unroll
      for (int c = 0; c < CH; ++c) {
        if (clt[c] <= K && K < clt[c] + ceq[c]) thrL[row] = v[c];
        if (clt[c] <= K + 1 && K + 1 < clt[c] + ceq[c]) thrH[row] = v[c];
      }
    }
  }
  __syncthreads();
  // prune + route (scaled H,V,D -> pr; raw cA -> cur; scaled cA at L==3)
  for (int e = tid; e < TOT; e += 1024) {
    const int s = e >> (2 * LOG2);
    const int row = e >> LOG2;
    const float sc = (s < 2) ? (s == 0 ? s0 : s1) : (s == 2 ? s2 : s3);
    const float thr = thrL[row] * (1.0f - FRAC) + thrH[row] * FRAC;
    const float co = tmp[e] * sc;
    const float val = (fabsf(co) > thr) ? co : 0.0f;
    if (s >= 1) pr[prOffset(L) + e - HH] = val;
    else {
      if (L == 3) pr[4080 + e] = val;
      cur[e] = tmp[e];
    }
  }
  __syncthreads();
}

// One block per image, 1024 threads. out = wavelet + bias (+ sum of partials).
__global__ __launch_bounds__(1024) void wavelet_kernel(
    const float* __restrict__ x, const float* __restrict__ bias,
    const float* __restrict__ scl, float* __restrict__ out,
    const float* __restrict__ partials, int addPartials) {
  __shared__ __align__(16) float sh[16384];    // 64 KB: cur|tmp|ab|pr
  float* cur = sh;
  float* tmp = sh + 4096;
  float* ab  = sh + 8192;   // L0 padded rows spill into pr[0..512) -- safe
  float* pr  = sh + 12288;
  float* thrL = cur + 2048;                    // dead region of cur
  float* thrH = cur + 2176;
  const int b = blockIdx.x, tid = threadIdx.x;
  const float* xi = x + (size_t)b * 4096;

  for (int i = tid; i < 1024; i += 1024)
    *(float4*)&cur[i * 4] = ((const float4*)xi)[i];
  __syncthreads();

  level_fwd<0>(cur, tmp, ab, pr, thrL, thrH, scl, tid);
  level_fwd<1>(cur, tmp, ab, pr, thrL, thrH, scl, tid);
  level_fwd<2>(cur, tmp, ab, pr, thrL, thrH, scl, tid);
  level_fwd<3>(cur, tmp, ab, pr, thrL, thrH, scl, tid);

#pragma unroll
  for (int l = 3; l >= 0; --l) {
    const int half = 64 >> (l + 1);
    const int hh = half * half;
    const int po = prOffset(l);
    const float* src = (l == 3) ? &pr[4080] : ((l & 1) ? tmp : cur);
    float* dst = (l & 1) ? cur : tmp;
    const int W2 = half * 2;
    for (int e = tid; e < hh; e += 1024) {
      const int i = e / half, j = e - i * half;
      const float cA = src[e];
      const float cH = pr[po + 0 * hh + i * half + j];
      const float cV = pr[po + 1 * hh + i * half + j];
      const float cD = pr[po + 2 * hh + i * half + j];
      const float a2 = (((cA + cH) + cV) + cD) * 0.5f;
      const float b2 = (((cA - cH) + cV) - cD) * 0.5f;
      const float c2 = (((cA + cH) - cV) - cD) * 0.5f;
      const float d2 = (((cA - cH) - cV) + cD) * 0.5f;
      dst[(i * 2) * W2 + j * 2]         = a2;
      dst[(i * 2) * W2 + j * 2 + 1]     = b2;
      dst[(i * 2 + 1) * W2 + j * 2]     = c2;
      dst[(i * 2 + 1) * W2 + j * 2 + 1] = d2;
    }
    __syncthreads();
  }
  // epilogue: out = wavelet + bias (+ sum of 16 split-K GEMM partials)
  float* o = out + (size_t)b * 4096;
  const float4* t4 = (const float4*)tmp;
  const float4* b4 = (const float4*)bias;
  for (int i = tid; i < 1024; i += 1024) {
    float4 t = t4[i], bb = b4[i];
    float4 s = {t.x + bb.x, t.y + bb.y, t.z + bb.z, t.w + bb.w};
    if (addPartials) {
#pragma unroll
      for (int ks = 0; ks < 16; ++ks) {
        const float4 p = *(const float4*)&partials[(size_t)ks * 524288 +
                                                   (size_t)b * 4096 + i * 4];
        s.x += p.x; s.y += p.y; s.z += p.z; s.w += p.w;
      }
    }
    ((float4*)o)[i] = s;
  }
}

// ---------------- GEMM v6: gload_lds 2-phase, split-K=16, partial stores ----
// grid 1024 = 64 n-tiles x 16 k-splits; block 256 = 4 waves; 4 blocks/CU.
// K-chunk 256 -> 8 steps of BK=32. A bf16 [128][32], B f32 [64][32], dbuf.
// Conflict-free via inverse-swizzled GLOBAL src + swizzled ds_read (rule 21).
__global__ __launch_bounds__(256, 4) void gemm_v6(
    const unsigned short* __restrict__ xb, const float* __restrict__ w,
    float* __restrict__ partials) {
  __shared__ __align__(16) unsigned short A_lds[2][128 * 32];
  __shared__ __align__(16) float B_lds[2][64 * 32];
  const int tid = threadIdx.x, lane = tid & 63, wv = tid >> 6;
  const int fr = lane & 15, kq = lane >> 4;
  const int nt = blockIdx.x & 63, ks = blockIdx.x >> 6;
  const int n0 = nt * 64, k0 = ks * 256;

  const int sA0 = tid, sA1 = 256 + tid;
  const int rA0 = sA0 >> 2, cA0 = (sA0 & 3) ^ ((rA0 >> 1) & 3);
  const int rA1 = sA1 >> 2, cA1 = (sA1 & 3) ^ ((rA1 >> 1) & 3);
  const unsigned short* aSrc0 = xb + (size_t)rA0 * 4096 + k0 + cA0 * 8;
  const unsigned short* aSrc1 = xb + (size_t)rA1 * 4096 + k0 + cA1 * 8;
  const int rB0 = sA0 >> 3, cB0 = (sA0 & 7) ^ (rB0 & 7);
  const int rB1 = sA1 >> 3, cB1 = (sA1 & 7) ^ (rB1 & 7);
  const float* bSrc0 = w + (size_t)(n0 + rB0) * 4096 + k0 + cB0 * 4;
  const float* bSrc1 = w + (size_t)(n0 + rB1) * 4096 + k0 + cB1 * 4;

  f32x4 acc[8];
#pragma unroll
  for (int mi = 0; mi < 8; ++mi) acc[mi] = f32x4{0.f, 0.f, 0.f, 0.f};

  const int aslot = kq ^ ((fr >> 1) & 3);
  const int R2 = wv * 16 + fr;
  const int bo0 = R2 * 128 + (((kq * 2 + 0) ^ (R2 & 7)) * 16);
  const int bo1 = R2 * 128 + (((kq * 2 + 1) ^ (R2 & 7)) * 16);

  auto STAGE = [&](int buf, int t) {
    gload16(aSrc0 + t * 32, (char*)&A_lds[buf][0] + tid * 16);
    gload16(aSrc1 + t * 32, (char*)&A_lds[buf][0] + (256 + tid) * 16);
    gload16(bSrc0 + t * 32, (char*)&B_lds[buf][0] + tid * 16);
    gload16(bSrc1 + t * 32, (char*)&B_lds[buf][0] + (256 + tid) * 16);
  };

  STAGE(0, 0);
  __syncthreads();
  int cur = 0;
#pragma unroll
  for (int t = 0; t < 8; ++t) {
    if (t < 7) STAGE(cur ^ 1, t + 1);
    const char* Ab = (const char*)&A_lds[cur][0];
    const char* Bb = (const char*)&B_lds[cur][0];
    const float4 b0 = *(const float4*)(Bb + bo0);
    const float4 b1 = *(const float4*)(Bb + bo1);
    const bf16x8 bb = pack8(b0, b1);
#pragma unroll
    for (int mi = 0; mi < 8; ++mi) {
      const bf16x8 af = *(const bf16x8*)(Ab + (mi * 16 + fr) * 64 + aslot * 16);
      acc[mi] = __builtin_amdgcn_mfma_f32_16x16x32_bf16(af, bb, acc[mi], 0, 0, 0);
    }
    __syncthreads();
    cur ^= 1;
  }

  // C/D layout: col=lane&15, row=(lane>>4)*4+j  [m89-verified]
  float* P = partials + (size_t)ks * 524288;
  const int col = n0 + wv * 16 + fr;
  const int rq = kq * 4;
#pragma unroll
  for (int mi = 0; mi < 8; ++mi)
#pragma unroll
    for (int j = 0; j < 4; ++j)
      P[(size_t)(mi * 16 + rq + j) * 4096 + col] = acc[mi][j];
}

// ---------------- fallback (no/small ws): round-1 style ---------------------
__global__ __launch_bounds__(256, 2) void gemm_kernel(
    const float* __restrict__ x, const float* __restrict__ w,
    float* __restrict__ out) {
  __shared__ __align__(16) unsigned short Asm[2][128][40];
  __shared__ __align__(16) unsigned short Bsm[2][64][40];
  const int tid = threadIdx.x;
  const int nt = blockIdx.x & 63, ks = blockIdx.x >> 6;
  const int n0 = nt * 64, k0 = ks * 512;
  const int q = tid & 7, r0 = tid >> 3;
  const int lane = tid & 63, wid = tid >> 6;
  const int wm = wid >> 1, wn = wid & 1;
  const int fr = lane & 15, k8 = (lane >> 4) * 8;

  f32x4 acc[4][2];
#pragma unroll
  for (int mi = 0; mi < 4; ++mi)
#pragma unroll
    for (int ni = 0; ni < 2; ++ni) acc[mi][ni] = f32x4{0.f, 0.f, 0.f, 0.f};

  float4 ra[4]; float4 rb[2];
#pragma unroll
  for (int p = 0; p < 4; ++p)
    ra[p] = *(const float4*)&x[(size_t)(r0 + p * 32) * 4096 + k0 + q * 4];
#pragma unroll
  for (int p = 0; p < 2; ++p)
    rb[p] = *(const float4*)&w[(size_t)(n0 + r0 + p * 32) * 4096 + k0 + q * 4];
#pragma unroll
  for (int p = 0; p < 4; ++p) {
    ushort4 pk = {f2bf(ra[p].x), f2bf(ra[p].y), f2bf(ra[p].z), f2bf(ra[p].w)};
    *(ushort4*)&Asm[0][r0 + p * 32][q * 4] = pk;
  }
#pragma unroll
  for (int p = 0; p < 2; ++p) {
    ushort4 pk = {f2bf(rb[p].x), f2bf(rb[p].y), f2bf(rb[p].z), f2bf(rb[p].w)};
    *(ushort4*)&Bsm[0][r0 + p * 32][q * 4] = pk;
  }
  __syncthreads();

  for (int t = 0; t < 16; ++t) {
    const int cb2 = t & 1;
    if (t < 15) {
      const int kg = k0 + (t + 1) * 32;
#pragma unroll
      for (int p = 0; p < 4; ++p)
        ra[p] = *(const float4*)&x[(size_t)(r0 + p * 32) * 4096 + kg + q * 4];
#pragma unroll
      for (int p = 0; p < 2; ++p)
        rb[p] = *(const float4*)&w[(size_t)(n0 + r0 + p * 32) * 4096 + kg + q * 4];
    }
    bf16x8 af[4], bg[2];
#pragma unroll
    for (int mi = 0; mi < 4; ++mi)
      af[mi] = *(const bf16x8*)&Asm[cb2][wm * 64 + mi * 16 + fr][k8];
#pragma unroll
    for (int ni = 0; ni < 2; ++ni)
      bg[ni] = *(const bf16x8*)&Bsm[cb2][wn * 32 + ni * 16 + fr][k8];
#pragma unroll
    for (int mi = 0; mi < 4; ++mi)
#pragma unroll
      for (int ni = 0; ni < 2; ++ni)
        acc[mi][ni] = __builtin_amdgcn_mfma_f32_16x16x32_bf16(af[mi], bg[ni],
                                                              acc[mi][ni], 0, 0, 0);
    if (t < 15) {
#pragma unroll
      for (int p = 0; p < 4; ++p) {
        ushort4 pk = {f2bf(ra[p].x), f2bf(ra[p].y), f2bf(ra[p].z), f2bf(ra[p].w)};
        *(ushort4*)&Asm[cb2 ^ 1][r0 + p * 32][q * 4] = pk;
      }
#pragma unroll
      for (int p = 0; p < 2; ++p) {
        ushort4 pk = {f2bf(rb[p].x), f2bf(rb[p].y), f2bf(rb[p].z), f2bf(rb[p].w)};
        *(ushort4*)&Bsm[cb2 ^ 1][r0 + p * 32][q * 4] = pk;
      }
    }
    __syncthreads();
  }

  const int rbase = wm * 64 + (lane >> 4) * 4;
  const int cbase = n0 + wn * 32 + fr;
#pragma unroll
  for (int mi = 0; mi < 4; ++mi)
#pragma unroll
    for (int ni = 0; ni < 2; ++ni)
#pragma unroll
      for (int j = 0; j < 4; ++j)
        atomicAdd(&out[(size_t)(rbase + mi * 16 + j) * 4096 + cbase + ni * 16],
                  acc[mi][ni][j]);
}

extern "C" void kernel_launch(void* const* d_in, const int* in_sizes, int n_in,
                              void* d_out, int out_size, void* d_ws, size_t ws_size,
                              hipStream_t stream) {
  const float* x    = (const float*)d_in[0];
  const float* w    = (const float*)d_in[1];
  const float* bias = (const float*)d_in[2];
  const float* scl  = (const float*)d_in[3];
  float* out = (float*)d_out;
  unsigned short* xbp = (unsigned short*)d_ws;
  float* partials = (float*)((char*)d_ws + (1 << 20));
  const size_t need = (1u << 20) + 16u * 524288u * 4u;    // 1MB xb + 32MB partials
  if (ws_size >= need) {
    hipLaunchKernelGGL(cvt_x, dim3(512), dim3(256), 0, stream, x, xbp);
    hipLaunchKernelGGL(gemm_v6, dim3(1024), dim3(256), 0, stream, xbp, w, partials);
    hipLaunchKernelGGL(wavelet_kernel, dim3(128), dim3(1024), 0, stream,
                       x, bias, scl, out, partials, 1);
  } else {
    hipLaunchKernelGGL(wavelet_kernel, dim3(128), dim3(1024), 0, stream,
                       x, bias, scl, out, (const float*)nullptr, 0);
    hipLaunchKernelGGL(gemm_kernel, dim3(512), dim3(256), 0, stream, x, w, out);
  }
}

// Round 10
// 127.706 us; speedup vs baseline: 1.0347x; 1.0347x over previous
//
#include <hip/hip_runtime.h>
#include <hip/hip_bf16.h>

typedef __attribute__((ext_vector_type(8))) short bf16x8;
typedef __attribute__((ext_vector_type(4))) float f32x4;

__device__ __forceinline__ unsigned short f2bf(float f) {
  unsigned int u = __float_as_uint(f);
  u += 0x7FFFu + ((u >> 16) & 1u);   // RTNE
  return (unsigned short)(u >> 16);
}

__device__ __forceinline__ bf16x8 pack8(float4 lo, float4 hi) {
  union { unsigned int u[4]; bf16x8 v; } r;
  asm("v_cvt_pk_bf16_f32 %0, %1, %2" : "=v"(r.u[0]) : "v"(lo.x), "v"(lo.y));
  asm("v_cvt_pk_bf16_f32 %0, %1, %2" : "=v"(r.u[1]) : "v"(lo.z), "v"(lo.w));
  asm("v_cvt_pk_bf16_f32 %0, %1, %2" : "=v"(r.u[2]) : "v"(hi.x), "v"(hi.y));
  asm("v_cvt_pk_bf16_f32 %0, %1, %2" : "=v"(r.u[3]) : "v"(hi.z), "v"(hi.w));
  return r.v;
}

__device__ __forceinline__ void gload16(const void* g, void* l) {
  __builtin_amdgcn_global_load_lds(
      (const __attribute__((address_space(1))) void*)g,
      (__attribute__((address_space(3))) void*)l, 16, 0, 0);
}

__host__ __device__ constexpr int prOffset(int l) {
  return (l == 0) ? 0 : (l == 1) ? 3072 : (l == 2) ? 3840 : 4032;
}

// ---------------- x -> bf16 (ws) --------------------------------------------
__global__ __launch_bounds__(256) void cvt_x(const float* __restrict__ x,
                                             unsigned short* __restrict__ xb) {
  const int i = blockIdx.x * 256 + threadIdx.x;          // 131072 float4s
  const float4 v = ((const float4*)x)[i];
  ushort4 pk = {f2bf(v.x), f2bf(v.y), f2bf(v.z), f2bf(v.w)};
  ((ushort4*)xb)[i] = pk;
}

// ---------------- wavelet level: wave-parallel quantile (pure shfl) ---------
// DWT -> tmp(raw)+ab(scaled abs, linear). Each 64-lane wave owns 64 contiguous
// coeffs = 64/HALF full rows. Rank counts via HALF-1 in-register shfl
// rotations; the rank-K / rank-K+1 values are broadcast to the row group via
// shfl_xor max-butterfly (values >= 0, selected lanes hold identical value).
// NO LDS involved in the threshold path -> no cross-lane store/load hazard.
template<int L>
__device__ __forceinline__ void level_fwd(float* cur, float* tmp, float* ab,
                                          float* pr,
                                          const float* __restrict__ scl, int tid) {
  constexpr int HALF = 32 >> L, LOG2 = 5 - L, HH = HALF * HALF, TOT = 4 * HH;
  constexpr int H = HALF * 2;
  constexpr float P = 0.4f * (float)(HALF - 1);
  constexpr int K = (int)P;
  constexpr float FRAC = P - (float)K;
  const float s0 = scl[4 * L + 0], s1 = scl[4 * L + 1];
  const float s2 = scl[4 * L + 2], s3 = scl[4 * L + 3];
  // DWT (raw) -> tmp; fused scaled-abs -> ab (linear row-major)
  for (int e = tid; e < HH; e += 1024) {
    const int i = e >> LOG2, j = e & (HALF - 1);
    const float a = cur[(i * 2) * H + j * 2];
    const float b = cur[(i * 2) * H + j * 2 + 1];
    const float c = cur[(i * 2 + 1) * H + j * 2];
    const float d = cur[(i * 2 + 1) * H + j * 2 + 1];
    const float vA = (((a + b) + c) + d) * 0.5f;
    const float vH = (((a - b) + c) - d) * 0.5f;
    const float vV = (((a + b) - c) - d) * 0.5f;
    const float vD = (((a - b) - c) + d) * 0.5f;
    tmp[e]          = vA;  ab[e]          = fabsf(vA * s0);
    tmp[HH + e]     = vH;  ab[HH + e]     = fabsf(vH * s1);
    tmp[2 * HH + e] = vV;  ab[2 * HH + e] = fabsf(vV * s2);
    tmp[3 * HH + e] = vD;  ab[3 * HH + e] = fabsf(vD * s3);
  }
  __syncthreads();
  // wave-parallel quantile + prune (registers + shfl only)
  {
    const int lane = tid & 63, wvi = tid >> 6;
    constexpr int NTASK = TOT / 64;              // 64,16,4,1
    const int idx = lane & (HALF - 1);
    const int laneBase = lane & ~(HALF - 1);
    for (int task = wvi; task < NTASK; task += 16) {
      const int e = task * 64 + lane;
      const float v = ab[e];                     // 64 contiguous: conflict-free
      int clt = 0, ceq = 1;                      // self counts as equal
#pragma unroll
      for (int s = 1; s < HALF; ++s) {
        const float u = __shfl(v, laneBase + ((idx + s) & (HALF - 1)), 64);
        clt += (u < v) ? 1 : 0;
        ceq += (u == v) ? 1 : 0;
      }
      float vlo = (clt <= K && K < clt + ceq) ? v : 0.0f;
      float vhi = (clt <= K + 1 && K + 1 < clt + ceq) ? v : 0.0f;
#pragma unroll
      for (int m = HALF / 2; m >= 1; m >>= 1) {  // stays within row group
        vlo = fmaxf(vlo, __shfl_xor(vlo, m, 64));
        vhi = fmaxf(vhi, __shfl_xor(vhi, m, 64));
      }
      const float thr = vlo * (1.0f - FRAC) + vhi * FRAC;
      const int sb = e >> (2 * LOG2);
      const float sc = (sb < 2) ? (sb == 0 ? s0 : s1) : (sb == 2 ? s2 : s3);
      const float co = tmp[e] * sc;
      const float val = (v > thr) ? co : 0.0f;   // v == |co|
      if (sb >= 1) pr[prOffset(L) + e - HH] = val;
      else {
        if (L == 3) pr[4080 + e] = val;
        cur[e] = tmp[e];                         // raw cA feeds next level
      }
    }
  }
  __syncthreads();
}

// One block per image, 1024 threads. out = wavelet + bias (+ sum of partials).
__global__ __launch_bounds__(1024) void wavelet_kernel(
    const float* __restrict__ x, const float* __restrict__ bias,
    const float* __restrict__ scl, float* __restrict__ out,
    const float* __restrict__ partials, int addPartials) {
  __shared__ __align__(16) float sh[16384];    // 64 KB: cur|tmp|ab|pr
  float* cur = sh;
  float* tmp = sh + 4096;
  float* ab  = sh + 8192;
  float* pr  = sh + 12288;
  const int b = blockIdx.x, tid = threadIdx.x;
  const float* xi = x + (size_t)b * 4096;

  for (int i = tid; i < 1024; i += 1024)
    *(float4*)&cur[i * 4] = ((const float4*)xi)[i];
  __syncthreads();

  level_fwd<0>(cur, tmp, ab, pr, scl, tid);
  level_fwd<1>(cur, tmp, ab, pr, scl, tid);
  level_fwd<2>(cur, tmp, ab, pr, scl, tid);
  level_fwd<3>(cur, tmp, ab, pr, scl, tid);

#pragma unroll
  for (int l = 3; l >= 0; --l) {
    const int half = 64 >> (l + 1);
    const int hh = half * half;
    const int po = prOffset(l);
    const float* src = (l == 3) ? &pr[4080] : ((l & 1) ? tmp : cur);
    float* dst = (l & 1) ? cur : tmp;
    const int W2 = half * 2;
    for (int e = tid; e < hh; e += 1024) {
      const int i = e / half, j = e - i * half;
      const float cA = src[e];
      const float cH = pr[po + 0 * hh + i * half + j];
      const float cV = pr[po + 1 * hh + i * half + j];
      const float cD = pr[po + 2 * hh + i * half + j];
      const float a2 = (((cA + cH) + cV) + cD) * 0.5f;
      const float b2 = (((cA - cH) + cV) - cD) * 0.5f;
      const float c2 = (((cA + cH) - cV) - cD) * 0.5f;
      const float d2 = (((cA - cH) - cV) + cD) * 0.5f;
      dst[(i * 2) * W2 + j * 2]         = a2;
      dst[(i * 2) * W2 + j * 2 + 1]     = b2;
      dst[(i * 2 + 1) * W2 + j * 2]     = c2;
      dst[(i * 2 + 1) * W2 + j * 2 + 1] = d2;
    }
    __syncthreads();
  }
  // epilogue: out = wavelet + bias (+ sum of 8 split-K GEMM partials)
  float* o = out + (size_t)b * 4096;
  const float4* t4 = (const float4*)tmp;
  const float4* b4 = (const float4*)bias;
  for (int i = tid; i < 1024; i += 1024) {
    float4 t = t4[i], bb = b4[i];
    float4 s = {t.x + bb.x, t.y + bb.y, t.z + bb.z, t.w + bb.w};
    if (addPartials) {
#pragma unroll
      for (int ks = 0; ks < 8; ++ks) {
        const float4 p = *(const float4*)&partials[(size_t)ks * 524288 +
                                                   (size_t)b * 4096 + i * 4];
        s.x += p.x; s.y += p.y; s.z += p.z; s.w += p.w;
      }
    }
    ((float4*)o)[i] = s;
  }
}

// ---------------- GEMM v5: gload_lds 2-phase, split-K=8, partial stores -----
// grid 512 = 64 n-tiles x 8 k-splits; block 256 = 4 waves. (round-5/7 proven)
__global__ __launch_bounds__(256, 4) void gemm_v5(
    const unsigned short* __restrict__ xb, const float* __restrict__ w,
    float* __restrict__ partials) {
  __shared__ __align__(16) unsigned short A_lds[2][128 * 32];
  __shared__ __align__(16) float B_lds[2][64 * 32];
  const int tid = threadIdx.x, lane = tid & 63, wv = tid >> 6;
  const int fr = lane & 15, kq = lane >> 4;
  const int nt = blockIdx.x & 63, ks = blockIdx.x >> 6;
  const int n0 = nt * 64, k0 = ks * 512;

  const int sA0 = tid, sA1 = 256 + tid;
  const int rA0 = sA0 >> 2, cA0 = (sA0 & 3) ^ ((rA0 >> 1) & 3);
  const int rA1 = sA1 >> 2, cA1 = (sA1 & 3) ^ ((rA1 >> 1) & 3);
  const unsigned short* aSrc0 = xb + (size_t)rA0 * 4096 + k0 + cA0 * 8;
  const unsigned short* aSrc1 = xb + (size_t)rA1 * 4096 + k0 + cA1 * 8;
  const int rB0 = sA0 >> 3, cB0 = (sA0 & 7) ^ (rB0 & 7);
  const int rB1 = sA1 >> 3, cB1 = (sA1 & 7) ^ (rB1 & 7);
  const float* bSrc0 = w + (size_t)(n0 + rB0) * 4096 + k0 + cB0 * 4;
  const float* bSrc1 = w + (size_t)(n0 + rB1) * 4096 + k0 + cB1 * 4;

  f32x4 acc[8];
#pragma unroll
  for (int mi = 0; mi < 8; ++mi) acc[mi] = f32x4{0.f, 0.f, 0.f, 0.f};

  const int aslot = kq ^ ((fr >> 1) & 3);
  const int R2 = wv * 16 + fr;
  const int bo0 = R2 * 128 + (((kq * 2 + 0) ^ (R2 & 7)) * 16);
  const int bo1 = R2 * 128 + (((kq * 2 + 1) ^ (R2 & 7)) * 16);

  auto STAGE = [&](int buf, int t) {
    gload16(aSrc0 + t * 32, (char*)&A_lds[buf][0] + tid * 16);
    gload16(aSrc1 + t * 32, (char*)&A_lds[buf][0] + (256 + tid) * 16);
    gload16(bSrc0 + t * 32, (char*)&B_lds[buf][0] + tid * 16);
    gload16(bSrc1 + t * 32, (char*)&B_lds[buf][0] + (256 + tid) * 16);
  };

  STAGE(0, 0);
  __syncthreads();
  int cur = 0;
#pragma unroll
  for (int t = 0; t < 16; ++t) {
    if (t < 15) STAGE(cur ^ 1, t + 1);
    const char* Ab = (const char*)&A_lds[cur][0];
    const char* Bb = (const char*)&B_lds[cur][0];
    const float4 b0 = *(const float4*)(Bb + bo0);
    const float4 b1 = *(const float4*)(Bb + bo1);
    const bf16x8 bb = pack8(b0, b1);
#pragma unroll
    for (int mi = 0; mi < 8; ++mi) {
      const bf16x8 af = *(const bf16x8*)(Ab + (mi * 16 + fr) * 64 + aslot * 16);
      acc[mi] = __builtin_amdgcn_mfma_f32_16x16x32_bf16(af, bb, acc[mi], 0, 0, 0);
    }
    __syncthreads();
    cur ^= 1;
  }

  // C/D layout: col=lane&15, row=(lane>>4)*4+j  [m89-verified]
  float* P = partials + (size_t)ks * 524288;
  const int col = n0 + wv * 16 + fr;
  const int rq = kq * 4;
#pragma unroll
  for (int mi = 0; mi < 8; ++mi)
#pragma unroll
    for (int j = 0; j < 4; ++j)
      P[(size_t)(mi * 16 + rq + j) * 4096 + col] = acc[mi][j];
}

// ---------------- fallback (no/small ws): round-1 style ---------------------
__global__ __launch_bounds__(256, 2) void gemm_kernel(
    const float* __restrict__ x, const float* __restrict__ w,
    float* __restrict__ out) {
  __shared__ __align__(16) unsigned short Asm[2][128][40];
  __shared__ __align__(16) unsigned short Bsm[2][64][40];
  const int tid = threadIdx.x;
  const int nt = blockIdx.x & 63, ks = blockIdx.x >> 6;
  const int n0 = nt * 64, k0 = ks * 512;
  const int q = tid & 7, r0 = tid >> 3;
  const int lane = tid & 63, wid = tid >> 6;
  const int wm = wid >> 1, wn = wid & 1;
  const int fr = lane & 15, k8 = (lane >> 4) * 8;

  f32x4 acc[4][2];
#pragma unroll
  for (int mi = 0; mi < 4; ++mi)
#pragma unroll
    for (int ni = 0; ni < 2; ++ni) acc[mi][ni] = f32x4{0.f, 0.f, 0.f, 0.f};

  float4 ra[4]; float4 rb[2];
#pragma unroll
  for (int p = 0; p < 4; ++p)
    ra[p] = *(const float4*)&x[(size_t)(r0 + p * 32) * 4096 + k0 + q * 4];
#pragma unroll
  for (int p = 0; p < 2; ++p)
    rb[p] = *(const float4*)&w[(size_t)(n0 + r0 + p * 32) * 4096 + k0 + q * 4];
#pragma unroll
  for (int p = 0; p < 4; ++p) {
    ushort4 pk = {f2bf(ra[p].x), f2bf(ra[p].y), f2bf(ra[p].z), f2bf(ra[p].w)};
    *(ushort4*)&Asm[0][r0 + p * 32][q * 4] = pk;
  }
#pragma unroll
  for (int p = 0; p < 2; ++p) {
    ushort4 pk = {f2bf(rb[p].x), f2bf(rb[p].y), f2bf(rb[p].z), f2bf(rb[p].w)};
    *(ushort4*)&Bsm[0][r0 + p * 32][q * 4] = pk;
  }
  __syncthreads();

  for (int t = 0; t < 16; ++t) {
    const int cb2 = t & 1;
    if (t < 15) {
      const int kg = k0 + (t + 1) * 32;
#pragma unroll
      for (int p = 0; p < 4; ++p)
        ra[p] = *(const float4*)&x[(size_t)(r0 + p * 32) * 4096 + kg + q * 4];
#pragma unroll
      for (int p = 0; p < 2; ++p)
        rb[p] = *(const float4*)&w[(size_t)(n0 + r0 + p * 32) * 4096 + kg + q * 4];
    }
    bf16x8 af[4], bg[2];
#pragma unroll
    for (int mi = 0; mi < 4; ++mi)
      af[mi] = *(const bf16x8*)&Asm[cb2][wm * 64 + mi * 16 + fr][k8];
#pragma unroll
    for (int ni = 0; ni < 2; ++ni)
      bg[ni] = *(const bf16x8*)&Bsm[cb2][wn * 32 + ni * 16 + fr][k8];
#pragma unroll
    for (int mi = 0; mi < 4; ++mi)
#pragma unroll
      for (int ni = 0; ni < 2; ++ni)
        acc[mi][ni] = __builtin_amdgcn_mfma_f32_16x16x32_bf16(af[mi], bg[ni],
                                                              acc[mi][ni], 0, 0, 0);
    if (t < 15) {
#pragma unroll
      for (int p = 0; p < 4; ++p) {
        ushort4 pk = {f2bf(ra[p].x), f2bf(ra[p].y), f2bf(ra[p].z), f2bf(ra[p].w)};
        *(ushort4*)&Asm[cb2 ^ 1][r0 + p * 32][q * 4] = pk;
      }
#pragma unroll
      for (int p = 0; p < 2; ++p) {
        ushort4 pk = {f2bf(rb[p].x), f2bf(rb[p].y), f2bf(rb[p].z), f2bf(rb[p].w)};
        *(ushort4*)&Bsm[cb2 ^ 1][r0 + p * 32][q * 4] = pk;
      }
    }
    __syncthreads();
  }

  const int rbase = wm * 64 + (lane >> 4) * 4;
  const int cbase = n0 + wn * 32 + fr;
#pragma unroll
  for (int mi = 0; mi < 4; ++mi)
#pragma unroll
    for (int ni = 0; ni < 2; ++ni)
#pragma unroll
      for (int j = 0; j < 4; ++j)
        atomicAdd(&out[(size_t)(rbase + mi * 16 + j) * 4096 + cbase + ni * 16],
                  acc[mi][ni][j]);
}

extern "C" void kernel_launch(void* const* d_in, const int* in_sizes, int n_in,
                              void* d_out, int out_size, void* d_ws, size_t ws_size,
                              hipStream_t stream) {
  const float* x    = (const float*)d_in[0];
  const float* w    = (const float*)d_in[1];
  const float* bias = (const float*)d_in[2];
  const float* scl  = (const float*)d_in[3];
  float* out = (float*)d_out;
  unsigned short* xbp = (unsigned short*)d_ws;
  float* partials = (float*)((char*)d_ws + (1 << 20));
  const size_t need = (1u << 20) + 8u * 524288u * 4u;     // 1MB xb + 16MB partials
  if (ws_size >= need) {
    hipLaunchKernelGGL(cvt_x, dim3(512), dim3(256), 0, stream, x, xbp);
    hipLaunchKernelGGL(gemm_v5, dim3(512), dim3(256), 0, stream, xbp, w, partials);
    hipLaunchKernelGGL(wavelet_kernel, dim3(128), dim3(1024), 0, stream,
                       x, bias, scl, out, partials, 1);
  } else {
    hipLaunchKernelGGL(wavelet_kernel, dim3(128), dim3(1024), 0, stream,
                       x, bias, scl, out, (const float*)nullptr, 0);
    hipLaunchKernelGGL(gemm_kernel, dim3(512), dim3(256), 0, stream, x, w, out);
  }
}